// Round 8
// baseline (122.333 us; speedup 1.0000x reference)
//
#include <hip/hip_runtime.h>

#define GG 1000
#define NPG 500
#define KK 8
#define N1 128
#define N2 128
#define NEG_SLOPE 0.45f
#define NTHREADS 512
#define NWAVES 8
#define CHUNK ((NPG + NWAVES - 1) / NWAVES)   // 63

__global__ __launch_bounds__(NTHREADS) void cluster_attn_kernel(
    const float* __restrict__ x,
    const float* __restrict__ W1,
    const float* __restrict__ b1,
    const float* __restrict__ Wa,
    const float* __restrict__ ba,
    const int*   __restrict__ cls,
    float*       __restrict__ out,
    int passes)                        // DIAGNOSTIC: 3x phase-1 reads
{
    __shared__ float s_acc[KK][N1];
    __shared__ int   s_cls[NPG];
    __shared__ int   s_order[NPG];
    __shared__ int   s_wcnt[NWAVES][KK];
    __shared__ int   s_start[KK];
    __shared__ float s_Lp[NWAVES][KK];
    __shared__ float s_fcnt[KK];
    __shared__ float s_ratio[KK];
    __shared__ float s_e[KK];

    const int g   = blockIdx.x;
    const int tid = threadIdx.x;
    const int w   = tid >> 6;
    const int l   = tid & 63;

    const int* clsg = cls + (size_t)g * NPG;
    float* accf = &s_acc[0][0];
    for (int i = tid; i < KK * N1; i += NTHREADS) accf[i] = 0.f;

    int myc = -1;
    if (tid < NPG) { myc = clsg[tid]; s_cls[tid] = myc; }

    unsigned long long mymask = 0;
    #pragma unroll
    for (int k = 0; k < KK; ++k) {
        unsigned long long m = __ballot(myc == k);
        if (l == 0) s_wcnt[w][k] = (int)__popcll(m);
        if (myc == k) mymask = m;
    }
    __syncthreads();

    if (tid == 0) {
        int run = 0; float d = 0.f;
        #pragma unroll
        for (int k = 0; k < KK; ++k) {
            int t = 0;
            #pragma unroll
            for (int ww = 0; ww < NWAVES; ++ww) t += s_wcnt[ww][k];
            s_start[k] = run; run += t;
            float c = (float)t; s_fcnt[k] = c; d += c * c;
        }
        #pragma unroll
        for (int k = 0; k < KK; ++k) s_ratio[k] = s_fcnt[k] / d;
    }
    __syncthreads();

    if (tid < NPG) {
        int before = 0;
        for (int ww = 0; ww < w; ++ww) before += s_wcnt[ww][myc];
        before += (int)__popcll(mymask & ((1ULL << l) - 1ULL));
        s_order[s_start[myc] + before] = tid | (myc << 12);
    }
    __syncthreads();

    // ---- phase 1 x `passes` (diagnostic): sorted run-walk, register adds ----
    const float2* x2 = (const float2*)(x + (size_t)g * NPG * N1);
    for (int pass = 0; pass < passes; ++pass) {
        int begin = w * CHUNK;
        int end   = begin + CHUNK; if (end > NPG) end = NPG;
        if (begin < end) {
            int cur = __builtin_amdgcn_readfirstlane(s_order[begin]) >> 12;
            float a0 = 0.f, a1 = 0.f;
            int e = begin;

#define STEP(P, V)                                                      \
            {                                                           \
                int c_ = (P) >> 12;                                     \
                if (c_ != cur) {                                        \
                    atomicAdd(&s_acc[cur][2 * l],     a0);              \
                    atomicAdd(&s_acc[cur][2 * l + 1], a1);              \
                    a0 = 0.f; a1 = 0.f; cur = c_;                       \
                }                                                       \
                a0 += (V).x; a1 += (V).y;                               \
            }

            for (; e + 4 <= end; e += 4) {
                int p0 = __builtin_amdgcn_readfirstlane(s_order[e]);
                int p1 = __builtin_amdgcn_readfirstlane(s_order[e + 1]);
                int p2 = __builtin_amdgcn_readfirstlane(s_order[e + 2]);
                int p3 = __builtin_amdgcn_readfirstlane(s_order[e + 3]);
                float2 v0 = x2[(size_t)(p0 & 0xFFF) * 64 + l];
                float2 v1 = x2[(size_t)(p1 & 0xFFF) * 64 + l];
                float2 v2 = x2[(size_t)(p2 & 0xFFF) * 64 + l];
                float2 v3 = x2[(size_t)(p3 & 0xFFF) * 64 + l];
                STEP(p0, v0) STEP(p1, v1) STEP(p2, v2) STEP(p3, v3)
            }
            for (; e < end; ++e) {
                int p = __builtin_amdgcn_readfirstlane(s_order[e]);
                float2 v = x2[(size_t)(p & 0xFFF) * 64 + l];
                STEP(p, v)
            }
#undef STEP
            atomicAdd(&s_acc[cur][2 * l],     a0);
            atomicAdd(&s_acc[cur][2 * l + 1], a1);
        }
    }
    __syncthreads();

    // ---- phase 2 (W1 once per block); scale csum by 1/passes ----
    {
        const float invp = 1.f / (float)passes;
        const int   jt  = (w << 4) + (l & 15);
        const int   fg  = l >> 4;
        const float b1j = b1[jt];
        const float Waj = Wa[jt];
        float p[KK];
        #pragma unroll
        for (int k = 0; k < KK; ++k) p[k] = 0.f;

        const float* w1p = W1 + (size_t)(fg * 32) * N2 + jt;
        #pragma unroll 4
        for (int i = 0; i < 32; ++i) {
            const float wv = w1p[(size_t)i * N2];
            const int   f  = fg * 32 + i;
            #pragma unroll
            for (int k = 0; k < KK; ++k)
                p[k] = fmaf(accf[k * N1 + f], wv, p[k]);
        }
        #pragma unroll
        for (int k = 0; k < KK; ++k) {
            float v = p[k];
            v += __shfl_xor(v, 16);
            v += __shfl_xor(v, 32);
            v *= invp;                           // undo the 3x accumulation
            float val = fmaf(v, s_ratio[k], b1j);
            float h = val > 0.f ? val : NEG_SLOPE * val;
            float c = h * Waj;
            c += __shfl_xor(c, 1);
            c += __shfl_xor(c, 2);
            c += __shfl_xor(c, 4);
            c += __shfl_xor(c, 8);
            if (l == 0) s_Lp[w][k] = c;
        }
    }
    __syncthreads();

    if (tid == 0) {
        float Lk[KK];
        #pragma unroll
        for (int k = 0; k < KK; ++k) {
            float s = ba[0];
            #pragma unroll
            for (int ww = 0; ww < NWAVES; ++ww) s += s_Lp[ww][k];
            Lk[k] = s;
        }
        float m = -1e30f;
        #pragma unroll
        for (int k = 0; k < KK; ++k)
            if (s_fcnt[k] > 0.f) m = fmaxf(m, Lk[k]);
        float ssum = 0.f;
        float ek[KK];
        #pragma unroll
        for (int k = 0; k < KK; ++k) {
            ek[k] = (s_fcnt[k] > 0.f) ? expf(Lk[k] - m) : 0.f;
            ssum += s_fcnt[k] * ek[k];
        }
        #pragma unroll
        for (int k = 0; k < KK; ++k) s_e[k] = ek[k] / ssum;
    }
    __syncthreads();

    float* outg = out + (size_t)g * NPG;
    for (int n = tid; n < NPG; n += NTHREADS) outg[n] = s_e[s_cls[n]];
}

extern "C" void kernel_launch(void* const* d_in, const int* in_sizes, int n_in,
                              void* d_out, int out_size, void* d_ws, size_t ws_size,
                              hipStream_t stream) {
    const float* x   = (const float*)d_in[0];
    const float* W1  = (const float*)d_in[1];
    const float* b1  = (const float*)d_in[2];
    const float* Wa  = (const float*)d_in[3];
    const float* ba  = (const float*)d_in[4];
    const int*   cls = (const int*)d_in[5];

    float* out = (float*)d_out;
    // DIAGNOSTIC ROUND: passes=3 so our dispatch outlasts the harness fill
    // kernels and surfaces in the rocprof top-5 with real counters.
    cluster_attn_kernel<<<GG, NTHREADS, 0, stream>>>(x, W1, b1, Wa, ba, cls, out, 3);
}

// Round 10
// 55.544 us; speedup vs baseline: 2.2024x; 2.2024x over previous
//
#include <hip/hip_runtime.h>

#define GG 1000
#define NPG 500
#define KK 8
#define N1 128
#define N2 128
#define NEG_SLOPE 0.45f
#define NTHREADS 512
#define NWAVES 8
#define CHUNK ((NPG + NWAVES - 1) / NWAVES)   // 63

typedef float fx2 __attribute__((ext_vector_type(2)));

__global__ __launch_bounds__(NTHREADS) void cluster_attn_kernel(
    const float* __restrict__ x,
    const float* __restrict__ W1,
    const float* __restrict__ b1,
    const float* __restrict__ Wa,
    const float* __restrict__ ba,
    const int*   __restrict__ cls,
    float*       __restrict__ out)
{
    __shared__ float s_acc[KK][N1];
    __shared__ int   s_cls[NPG];
    __shared__ int   s_order[NPG];
    __shared__ int   s_wcnt[NWAVES][KK];
    __shared__ int   s_start[KK];
    __shared__ float s_Lp[NWAVES][KK];
    __shared__ float s_fcnt[KK];
    __shared__ float s_ratio[KK];
    __shared__ float s_e[KK];

    const int g   = blockIdx.x;
    const int tid = threadIdx.x;
    const int w   = tid >> 6;
    const int l   = tid & 63;

    const int* clsg = cls + (size_t)g * NPG;
    float* accf = &s_acc[0][0];
    for (int i = tid; i < KK * N1; i += NTHREADS) accf[i] = 0.f;

    int myc = -1;
    if (tid < NPG) { myc = clsg[tid]; s_cls[tid] = myc; }

    // ---- deterministic bucket ranks via wave ballots (no atomics) ----
    unsigned long long mymask = 0;
    #pragma unroll
    for (int k = 0; k < KK; ++k) {
        unsigned long long m = __ballot(myc == k);
        if (l == 0) s_wcnt[w][k] = (int)__popcll(m);
        if (myc == k) mymask = m;
    }
    __syncthreads();

    if (tid == 0) {
        int run = 0; float d = 0.f;
        #pragma unroll
        for (int k = 0; k < KK; ++k) {
            int t = 0;
            #pragma unroll
            for (int ww = 0; ww < NWAVES; ++ww) t += s_wcnt[ww][k];
            s_start[k] = run; run += t;
            float c = (float)t; s_fcnt[k] = c; d += c * c;
        }
        #pragma unroll
        for (int k = 0; k < KK; ++k) s_ratio[k] = s_fcnt[k] / d;
    }
    __syncthreads();

    if (tid < NPG) {
        int before = 0;
        for (int ww = 0; ww < w; ++ww) before += s_wcnt[ww][myc];
        before += (int)__popcll(mymask & ((1ULL << l) - 1ULL));
        s_order[s_start[myc] + before] = tid | (myc << 12);
    }
    __syncthreads();

    // ---- phase 1: sorted run-walk; CACHE/STREAM SPLIT by node parity.
    //      even node -> normal load (L3-resident half, no capacity pressure)
    //      odd  node -> nontemporal load (HBM stream, no L3 pollution)      ----
    const fx2* x2 = (const fx2*)(x + (size_t)g * NPG * N1);
    {
        int begin = w * CHUNK;
        int end   = begin + CHUNK; if (end > NPG) end = NPG;
        if (begin < end) {
            int cur = __builtin_amdgcn_readfirstlane(s_order[begin]) >> 12;
            float a0 = 0.f, a1 = 0.f;
            int e = begin;

#define LOADX(ND)                                                       \
    (((ND) & 1) ? __builtin_nontemporal_load(x2 + (size_t)(ND) * 64 + l)\
                : x2[(size_t)(ND) * 64 + l])

#define STEP(P, V)                                                      \
            {                                                           \
                int c_ = (P) >> 12;                                     \
                if (c_ != cur) {            /* wave-uniform, rare */    \
                    atomicAdd(&s_acc[cur][2 * l],     a0);              \
                    atomicAdd(&s_acc[cur][2 * l + 1], a1);              \
                    a0 = 0.f; a1 = 0.f; cur = c_;                       \
                }                                                       \
                a0 += (V).x; a1 += (V).y;                               \
            }

            for (; e + 4 <= end; e += 4) {
                int p0 = __builtin_amdgcn_readfirstlane(s_order[e]);
                int p1 = __builtin_amdgcn_readfirstlane(s_order[e + 1]);
                int p2 = __builtin_amdgcn_readfirstlane(s_order[e + 2]);
                int p3 = __builtin_amdgcn_readfirstlane(s_order[e + 3]);
                fx2 v0 = LOADX(p0 & 0xFFF);
                fx2 v1 = LOADX(p1 & 0xFFF);
                fx2 v2 = LOADX(p2 & 0xFFF);
                fx2 v3 = LOADX(p3 & 0xFFF);
                STEP(p0, v0) STEP(p1, v1) STEP(p2, v2) STEP(p3, v3)
            }
            for (; e < end; ++e) {
                int p = __builtin_amdgcn_readfirstlane(s_order[e]);
                fx2 v = LOADX(p & 0xFFF);
                STEP(p, v)
            }
#undef STEP
#undef LOADX
            atomicAdd(&s_acc[cur][2 * l],     a0);
            atomicAdd(&s_acc[cur][2 * l + 1], a1);
        }
    }
    __syncthreads();

    // ---- phase 2 (W1 read once per block): wave w owns j-tile [16w,16w+16) ----
    {
        const int   jt  = (w << 4) + (l & 15);
        const int   fg  = l >> 4;
        const float b1j = b1[jt];
        const float Waj = Wa[jt];
        float p[KK];
        #pragma unroll
        for (int k = 0; k < KK; ++k) p[k] = 0.f;

        const float* w1p = W1 + (size_t)(fg * 32) * N2 + jt;
        #pragma unroll 4
        for (int i = 0; i < 32; ++i) {
            const float wv = w1p[(size_t)i * N2];
            const int   f  = fg * 32 + i;
            #pragma unroll
            for (int k = 0; k < KK; ++k)
                p[k] = fmaf(accf[k * N1 + f], wv, p[k]);
        }
        #pragma unroll
        for (int k = 0; k < KK; ++k) {
            float v = p[k];
            v += __shfl_xor(v, 16);
            v += __shfl_xor(v, 32);
            float val = fmaf(v, s_ratio[k], b1j);
            float h = val > 0.f ? val : NEG_SLOPE * val;
            float c = h * Waj;
            c += __shfl_xor(c, 1);
            c += __shfl_xor(c, 2);
            c += __shfl_xor(c, 4);
            c += __shfl_xor(c, 8);
            if (l == 0) s_Lp[w][k] = c;
        }
    }
    __syncthreads();

    // ---- phase 3: logits -> count-weighted softmax ----
    if (tid == 0) {
        float Lk[KK];
        #pragma unroll
        for (int k = 0; k < KK; ++k) {
            float s = ba[0];
            #pragma unroll
            for (int ww = 0; ww < NWAVES; ++ww) s += s_Lp[ww][k];
            Lk[k] = s;
        }
        float m = -1e30f;
        #pragma unroll
        for (int k = 0; k < KK; ++k)
            if (s_fcnt[k] > 0.f) m = fmaxf(m, Lk[k]);
        float ssum = 0.f;
        float ek[KK];
        #pragma unroll
        for (int k = 0; k < KK; ++k) {
            ek[k] = (s_fcnt[k] > 0.f) ? expf(Lk[k] - m) : 0.f;
            ssum += s_fcnt[k] * ek[k];
        }
        #pragma unroll
        for (int k = 0; k < KK; ++k) s_e[k] = ek[k] / ssum;
    }
    __syncthreads();

    // ---- phase 4: per-node output = table lookup ----
    float* outg = out + (size_t)g * NPG;
    for (int n = tid; n < NPG; n += NTHREADS) outg[n] = s_e[s_cls[n]];
}

extern "C" void kernel_launch(void* const* d_in, const int* in_sizes, int n_in,
                              void* d_out, int out_size, void* d_ws, size_t ws_size,
                              hipStream_t stream) {
    const float* x   = (const float*)d_in[0];
    const float* W1  = (const float*)d_in[1];
    const float* b1  = (const float*)d_in[2];
    const float* Wa  = (const float*)d_in[3];
    const float* ba  = (const float*)d_in[4];
    const int*   cls = (const int*)d_in[5];

    float* out = (float*)d_out;
    cluster_attn_kernel<<<GG, NTHREADS, 0, stream>>>(x, W1, b1, Wa, ba, cls, out);
}